// Round 3
// baseline (600.342 us; speedup 1.0000x reference)
//
#include <hip/hip_runtime.h>

#define BB 4
#define CC 256
#define NN 4096

typedef __attribute__((ext_vector_type(8))) short bh8;
typedef __attribute__((ext_vector_type(4))) float f32x4;

// workspace layout (bytes)
#define WPK_OFF  0                        // 20*8*64*8 bf16 = 163840 (B-frag packed W)
#define BALL_OFF 163840                   // 320 f32
#define QBF_OFF  165888                   // B*N*32 bf16 = 1 MB
#define KBF_OFF  (165888 + 1048576)
#define VBF_OFF  (165888 + 2097152)       // B*C*N bf16 = 8 MB  -> end ~10.4 MB

typedef const __attribute__((address_space(1))) void* gas_t;
typedef __attribute__((address_space(3))) void* las_t;
__device__ inline void gld16(const void* g, void* l) {
    __builtin_amdgcn_global_load_lds((gas_t)g, (las_t)l, 16, 0, 0);
}

__device__ inline int pack2bf(float a, float b) {
    unsigned ua = __builtin_bit_cast(unsigned, a) + 0x8000u;
    unsigned ub = __builtin_bit_cast(unsigned, b) + 0x8000u;
    return (int)__builtin_amdgcn_perm(ub, ua, 0x07060302u);
}
__device__ inline short f2bf1(float a) {
    return (short)((__builtin_bit_cast(unsigned, a) + 0x8000u) >> 16);
}

// ---------------- prep: Wpk B-fragments + ball
// Wpk entry (mt,ck,lane): m = mt*16+(lane&15), c = ck*32+(lane>>4)*8+e  (e=0..7)
__global__ __launch_bounds__(256) void prep_w(const float* __restrict__ Wq,
        const float* __restrict__ bq, const float* __restrict__ Wk,
        const float* __restrict__ bk, const float* __restrict__ Wv,
        const float* __restrict__ bv, short* __restrict__ Wpk,
        float* __restrict__ ball) {
    int tid = blockIdx.x * 256 + threadIdx.x;
    if (tid < 10240) {
        int lane = tid & 63;
        int fc = tid >> 6;                 // mt*8 + ck
        int mt = fc >> 3, ck = fc & 7;
        int m = mt * 16 + (lane & 15);
        int c0 = ck * 32 + (lane >> 4) * 8;
        const float* wrow;
        if (m < 32)      wrow = Wq + m * 256;
        else if (m < 64) wrow = Wk + (m - 32) * 256;
        else             wrow = Wv + (m - 64) * 256;
        int d[4];
        #pragma unroll
        for (int p = 0; p < 4; ++p)
            d[p] = pack2bf(wrow[c0 + 2 * p], wrow[c0 + 2 * p + 1]);
        *(int4*)(Wpk + tid * 8) = make_int4(d[0], d[1], d[2], d[3]);
    }
    if (tid < 320) {
        float b2 = tid < 32 ? bq[tid] : (tid < 64 ? bk[tid - 32] : bv[tid - 64]);
        ball[tid] = b2;
    }
}

// ---------------- projections as MFMA GEMM: out[n][m] = x^T W^T + b
// wave = one 16-row n-tile; A-frags built in-register from coalesced x loads.
__global__ __launch_bounds__(256) void proj(const float* __restrict__ x,
        const short* __restrict__ Wpk, const float* __restrict__ ball,
        short* __restrict__ qbf, short* __restrict__ kbf,
        short* __restrict__ vbf) {
    int t = threadIdx.x;
    int w = t >> 6, lane = t & 63, quad = lane >> 4, c15 = lane & 15;
    int tile = blockIdx.x * 4 + w;         // 0..1023
    int b = tile >> 8, n0 = (tile & 255) * 16;
    const float* xb = x + (size_t)b * CC * NN;

    // A-frags: m = c15 (row n0+c15), k = quad*8+e, over 8 k-chunks of 32
    bh8 af[8];
    #pragma unroll
    for (int ck = 0; ck < 8; ++ck) {
        float v[8];
        #pragma unroll
        for (int e = 0; e < 8; ++e)
            v[e] = xb[(size_t)(ck * 32 + quad * 8 + e) * NN + n0 + c15];
        int d[4];
        #pragma unroll
        for (int p = 0; p < 4; ++p) d[p] = pack2bf(v[2 * p], v[2 * p + 1]);
        af[ck] = __builtin_bit_cast(bh8, make_int4(d[0], d[1], d[2], d[3]));
    }

    // m-tiles in pairs: two independent MFMA chains for ILP
    #pragma unroll 2
    for (int mp = 0; mp < 10; ++mp) {
        int mtA = mp * 2, mtB = mp * 2 + 1;
        float blA = ball[mtA * 16 + c15], blB = ball[mtB * 16 + c15];
        f32x4 accA = {blA, blA, blA, blA}, accB = {blB, blB, blB, blB};
        #pragma unroll
        for (int ck = 0; ck < 8; ++ck) {
            bh8 wfA = *(const bh8*)(Wpk + ((mtA * 8 + ck) * 64 + lane) * 8);
            bh8 wfB = *(const bh8*)(Wpk + ((mtB * 8 + ck) * 64 + lane) * 8);
            accA = __builtin_amdgcn_mfma_f32_16x16x32_bf16(af[ck], wfA, accA, 0, 0, 0);
            accB = __builtin_amdgcn_mfma_f32_16x16x32_bf16(af[ck], wfB, accB, 0, 0, 0);
        }
        // D: col=c15 -> m, row=quad*4+r -> n
        #pragma unroll
        for (int half = 0; half < 2; ++half) {
            int mt = mp * 2 + half;
            f32x4 acc = half ? accB : accA;
            if (mt < 4) {
                short* dst = (mt < 2) ? qbf : kbf;
                int m = (mt & 1) * 16 + c15;
                #pragma unroll
                for (int r = 0; r < 4; ++r)
                    dst[(size_t)(b * NN + n0 + quad * 4 + r) * 32 + m] = f2bf1(acc[r]);
            } else {
                int c = mt * 16 + c15 - 64;
                int2 pk;
                pk.x = pack2bf(acc[0], acc[1]);
                pk.y = pack2bf(acc[2], acc[3]);
                *(int2*)(vbf + (size_t)b * CC * NN + (size_t)c * NN + n0 + quad * 4) = pk;
            }
        }
    }
}

// ---------------- fused flash attention: 4 waves = (row-half wr) x (j-half wj)
__global__ __launch_bounds__(256, 1) void flash_attn(
        const short* __restrict__ qbf, const short* __restrict__ kbf,
        const short* __restrict__ vbf, const float* __restrict__ x,
        const float* __restrict__ gamma, float* __restrict__ out) {
    __shared__ short lds_s[73728];         // 144 KB: V 4x32KB + P 4x4KB

    int bid = blockIdx.x;
    int b = bid & 3, it = bid >> 2;        // batch pinned to XCD pair (L2)
    int t = threadIdx.x;
    int w = t >> 6, lane = t & 63, quad = lane >> 4, c15 = lane & 15;
    int wj = w >> 1, wr = w & 1;
    int i0 = it * 64 + wr * 32;
    int jb = wj * 2048;

    const short* qb = qbf + (size_t)b * NN * 32;
    const short* kb = kbf + (size_t)b * NN * 32;
    const short* vb = vbf + (size_t)b * CC * NN;

    // Q fragments (B-operand) for two 16-row subtiles
    bh8 qf0 = *(const bh8*)(qb + (size_t)(i0 + c15) * 32 + quad * 8);
    bh8 qf1 = *(const bh8*)(qb + (size_t)(i0 + 16 + c15) * 32 + quad * 8);

    // V staging: wave stages rows [wr*128, wr*128+128) of tile wj
    const short* vsg = vb + (size_t)(wr * 128 + (lane >> 3)) * NN
                          + ((lane & 7) ^ ((lane >> 3) & 7)) * 8 + jb;

    f32x4 acc0[16], acc1[16];
    #pragma unroll
    for (int ct = 0; ct < 16; ++ct) {
        acc0[ct] = (f32x4){0.f, 0.f, 0.f, 0.f};
        acc1[ct] = (f32x4){0.f, 0.f, 0.f, 0.f};
    }
    float lsum0 = 0.f, lsum1 = 0.f;
    const f32x4 initc = {-12.f, -12.f, -12.f, -12.f};  // softmax shift in C
    short* pw0 = lds_s + 65536 + w * 2048;
    short* pw1 = pw0 + 1024;

    // prologue: stage buf0 + load kf for step 0
    {
        short* vd = lds_s + (0 * 2 + wj) * 16384 + wr * 8192;
        #pragma unroll
        for (int cc = 0; cc < 16; ++cc) gld16(vsg + cc * 8 * NN, vd + cc * 512);
    }
    bh8 kf[4];
    #pragma unroll
    for (int s = 0; s < 4; ++s)
        kf[s] = *(const bh8*)(kb + (size_t)(jb + s * 16 + c15) * 32 + quad * 8);
    __syncthreads();

    for (int step = 0; step < 32; ++step) {
        int cur = step & 1;
        bh8 kfn[4];
        if (step < 31) {
            int j0n = (step + 1) * 64;
            short* vd = lds_s + ((cur ^ 1) * 2 + wj) * 16384 + wr * 8192;
            #pragma unroll
            for (int cc = 0; cc < 16; ++cc)
                gld16(vsg + j0n + cc * 8 * NN, vd + cc * 512);
            #pragma unroll
            for (int s = 0; s < 4; ++s)
                kfn[s] = *(const bh8*)(kb + (size_t)(jb + j0n + s * 16 + c15) * 32 + quad * 8);
        }
        const short* Vb = lds_s + (cur * 2 + wj) * 16384;

        // S^T = K·Q^T (A=K rows j, B=Q rows i), then exp + pack + P->LDS
        #pragma unroll
        for (int s = 0; s < 4; ++s) {
            f32x4 sa0 = __builtin_amdgcn_mfma_f32_16x16x32_bf16(kf[s], qf0, initc, 0, 0, 0);
            f32x4 sa1 = __builtin_amdgcn_mfma_f32_16x16x32_bf16(kf[s], qf1, initc, 0, 0, 0);
            float p0[4], p1[4];
            #pragma unroll
            for (int r = 0; r < 4; ++r) {
                p0[r] = __expf(sa0[r]); lsum0 += p0[r];
                p1[r] = __expf(sa1[r]); lsum1 += p1[r];
            }
            int soff = c15 * 64 + (((s * 2 + (quad >> 1)) ^ (c15 & 7)) * 8) + (quad & 1) * 4;
            *(int2*)(pw0 + soff) = make_int2(pack2bf(p0[0], p0[1]), pack2bf(p0[2], p0[3]));
            *(int2*)(pw1 + soff) = make_int2(pack2bf(p1[0], p1[1]), pack2bf(p1[2], p1[3]));
        }
        __asm__ volatile("s_waitcnt lgkmcnt(0)" ::: "memory");
        bh8 pf0[2], pf1[2];
        #pragma unroll
        for (int kk = 0; kk < 2; ++kk) {
            int poff = c15 * 64 + (((kk * 4 + quad) ^ (c15 & 7)) * 8);
            pf0[kk] = *(const bh8*)(pw0 + poff);
            pf1[kk] = *(const bh8*)(pw1 + poff);
        }
        // O^T += V·P^T ; V fragment feeds both row subtiles
        #pragma unroll
        for (int kk = 0; kk < 2; ++kk) {
            #pragma unroll
            for (int ct = 0; ct < 16; ++ct) {
                int c = ct * 16 + c15;
                bh8 vf = *(const bh8*)(Vb + c * 64 + (((kk * 4 + quad) ^ (c15 & 7)) * 8));
                acc0[ct] = __builtin_amdgcn_mfma_f32_16x16x32_bf16(vf, pf0[kk], acc0[ct], 0, 0, 0);
                acc1[ct] = __builtin_amdgcn_mfma_f32_16x16x32_bf16(vf, pf1[kk], acc1[ct], 0, 0, 0);
            }
        }
        if (step < 31) {
            #pragma unroll
            for (int s = 0; s < 4; ++s) kf[s] = kfn[s];
        }
        __syncthreads();
    }

    // per-row softmax denominators (partial over this wave's j-half)
    lsum0 += __shfl_xor(lsum0, 16); lsum0 += __shfl_xor(lsum0, 32);
    lsum1 += __shfl_xor(lsum1, 16); lsum1 += __shfl_xor(lsum1, 32);

    // combine j-halves through LDS: give away ct-half (1-wj), keep half wj
    float* cr = (float*)lds_s;             // reuses V region (64 KB used)
    float* lf = (float*)(lds_s + 65536);   // reuses P region
    int hg = 1 - wj;
    #pragma unroll
    for (int ctl = 0; ctl < 8; ++ctl) {
        *(f32x4*)(cr + wr * 8192 + hg * 4096 + (ctl * 2 + 0) * 256 + lane * 4) = acc0[hg * 8 + ctl];
        *(f32x4*)(cr + wr * 8192 + hg * 4096 + (ctl * 2 + 1) * 256 + lane * 4) = acc1[hg * 8 + ctl];
    }
    if (quad == 0) {
        lf[(wr * 2 + wj) * 32 + 0 * 16 + c15] = lsum0;
        lf[(wr * 2 + wj) * 32 + 1 * 16 + c15] = lsum1;
    }
    __syncthreads();
    #pragma unroll
    for (int ctl = 0; ctl < 8; ++ctl) {
        acc0[wj * 8 + ctl] += *(f32x4*)(cr + wr * 8192 + wj * 4096 + (ctl * 2 + 0) * 256 + lane * 4);
        acc1[wj * 8 + ctl] += *(f32x4*)(cr + wr * 8192 + wj * 4096 + (ctl * 2 + 1) * 256 + lane * 4);
    }
    float lt0 = lsum0 + lf[(wr * 2 + (1 - wj)) * 32 + 0 * 16 + c15];
    float lt1 = lsum1 + lf[(wr * 2 + (1 - wj)) * 32 + 1 * 16 + c15];
    float linv0 = 1.0f / lt0, linv1 = 1.0f / lt1;

    float g = gamma[0];
    const float* xb2 = x + (size_t)b * CC * NN;
    float* ob = out + (size_t)b * CC * NN;
    int ia = i0 + c15, ib2 = i0 + 16 + c15;
    #pragma unroll
    for (int ctl = 0; ctl < 8; ++ctl) {
        int ct = wj * 8 + ctl;
        #pragma unroll
        for (int r = 0; r < 4; ++r) {
            int c = ct * 16 + quad * 4 + r;
            ob[(size_t)c * NN + ia]  = g * acc0[ct][r] * linv0 + xb2[(size_t)c * NN + ia];
            ob[(size_t)c * NN + ib2] = g * acc1[ct][r] * linv1 + xb2[(size_t)c * NN + ib2];
        }
    }
}

extern "C" void kernel_launch(void* const* d_in, const int* in_sizes, int n_in,
                              void* d_out, int out_size, void* d_ws, size_t ws_size,
                              hipStream_t stream) {
    const float* x     = (const float*)d_in[0];
    const float* Wq    = (const float*)d_in[1];
    const float* bq    = (const float*)d_in[2];
    const float* Wk    = (const float*)d_in[3];
    const float* bk    = (const float*)d_in[4];
    const float* Wv    = (const float*)d_in[5];
    const float* bv    = (const float*)d_in[6];
    const float* gamma = (const float*)d_in[7];
    float* out = (float*)d_out;
    char*  ws  = (char*)d_ws;
    short* Wpk  = (short*)(ws + WPK_OFF);
    float* ball = (float*)(ws + BALL_OFF);
    short* qbf  = (short*)(ws + QBF_OFF);
    short* kbf  = (short*)(ws + KBF_OFF);
    short* vbf  = (short*)(ws + VBF_OFF);

    prep_w<<<40, 256, 0, stream>>>(Wq, bq, Wk, bk, Wv, bv, Wpk, ball);
    proj<<<256, 256, 0, stream>>>(x, Wpk, ball, qbf, kbf, vbf);
    flash_attn<<<256, 256, 0, stream>>>(qbf, kbf, vbf, x, gamma, out);
}

// Round 5
// 160.307 us; speedup vs baseline: 3.7450x; 3.7450x over previous
//
#include <hip/hip_runtime.h>

#define BB 4
#define CC 256
#define NN 4096

typedef __attribute__((ext_vector_type(8))) short bh8;
typedef __attribute__((ext_vector_type(4))) float f32x4;

// workspace layout (bytes)
#define WPK_OFF  0                        // 20*8*64*8 bf16 = 163840 (B-frag packed W)
#define BALL_OFF 163840                   // 320 f32
#define QBF_OFF  165888                   // B*N*32 bf16 = 1 MB
#define KBF_OFF  (165888 + 1048576)
#define VBF_OFF  (165888 + 2097152)       // B*C*N bf16 = 8 MB  -> end ~10.4 MB

typedef const __attribute__((address_space(1))) void* gas_t;
typedef __attribute__((address_space(3))) void* las_t;
__device__ inline void gld16(const void* g, void* l) {
    __builtin_amdgcn_global_load_lds((gas_t)g, (las_t)l, 16, 0, 0);
}

__device__ inline int pack2bf(float a, float b) {
    unsigned ua = __builtin_bit_cast(unsigned, a) + 0x8000u;
    unsigned ub = __builtin_bit_cast(unsigned, b) + 0x8000u;
    return (int)__builtin_amdgcn_perm(ub, ua, 0x07060302u);
}
__device__ inline short f2bf1(float a) {
    return (short)((__builtin_bit_cast(unsigned, a) + 0x8000u) >> 16);
}

// ---------------- prep: Wpk B-fragments + ball
__global__ __launch_bounds__(256) void prep_w(const float* __restrict__ Wq,
        const float* __restrict__ bq, const float* __restrict__ Wk,
        const float* __restrict__ bk, const float* __restrict__ Wv,
        const float* __restrict__ bv, short* __restrict__ Wpk,
        float* __restrict__ ball) {
    int tid = blockIdx.x * 256 + threadIdx.x;
    if (tid < 10240) {
        int lane = tid & 63;
        int fc = tid >> 6;                 // mt*8 + ck
        int mt = fc >> 3, ck = fc & 7;
        int m = mt * 16 + (lane & 15);
        int c0 = ck * 32 + (lane >> 4) * 8;
        const float* wrow;
        if (m < 32)      wrow = Wq + m * 256;
        else if (m < 64) wrow = Wk + (m - 32) * 256;
        else             wrow = Wv + (m - 64) * 256;
        int d[4];
        #pragma unroll
        for (int p = 0; p < 4; ++p)
            d[p] = pack2bf(wrow[c0 + 2 * p], wrow[c0 + 2 * p + 1]);
        *(int4*)(Wpk + tid * 8) = make_int4(d[0], d[1], d[2], d[3]);
    }
    if (tid < 320) {
        float b2 = tid < 32 ? bq[tid] : (tid < 64 ? bk[tid - 32] : bv[tid - 64]);
        ball[tid] = b2;
    }
}

// ---------------- projections as MFMA GEMM (unchanged; counters will judge)
__global__ __launch_bounds__(256) void proj(const float* __restrict__ x,
        const short* __restrict__ Wpk, const float* __restrict__ ball,
        short* __restrict__ qbf, short* __restrict__ kbf,
        short* __restrict__ vbf) {
    int t = threadIdx.x;
    int w = t >> 6, lane = t & 63, quad = lane >> 4, c15 = lane & 15;
    int tile = blockIdx.x * 4 + w;         // 0..1023
    int b = tile >> 8, n0 = (tile & 255) * 16;
    const float* xb = x + (size_t)b * CC * NN;

    bh8 af[8];
    #pragma unroll
    for (int ck = 0; ck < 8; ++ck) {
        float v[8];
        #pragma unroll
        for (int e = 0; e < 8; ++e)
            v[e] = xb[(size_t)(ck * 32 + quad * 8 + e) * NN + n0 + c15];
        int d[4];
        #pragma unroll
        for (int p = 0; p < 4; ++p) d[p] = pack2bf(v[2 * p], v[2 * p + 1]);
        af[ck] = __builtin_bit_cast(bh8, make_int4(d[0], d[1], d[2], d[3]));
    }

    #pragma unroll 2
    for (int mp = 0; mp < 10; ++mp) {
        int mtA = mp * 2, mtB = mp * 2 + 1;
        float blA = ball[mtA * 16 + c15], blB = ball[mtB * 16 + c15];
        f32x4 accA = {blA, blA, blA, blA}, accB = {blB, blB, blB, blB};
        #pragma unroll
        for (int ck = 0; ck < 8; ++ck) {
            bh8 wfA = *(const bh8*)(Wpk + ((mtA * 8 + ck) * 64 + lane) * 8);
            bh8 wfB = *(const bh8*)(Wpk + ((mtB * 8 + ck) * 64 + lane) * 8);
            accA = __builtin_amdgcn_mfma_f32_16x16x32_bf16(af[ck], wfA, accA, 0, 0, 0);
            accB = __builtin_amdgcn_mfma_f32_16x16x32_bf16(af[ck], wfB, accB, 0, 0, 0);
        }
        #pragma unroll
        for (int half = 0; half < 2; ++half) {
            int mt = mp * 2 + half;
            f32x4 acc = half ? accB : accA;
            if (mt < 4) {
                short* dst = (mt < 2) ? qbf : kbf;
                int m = (mt & 1) * 16 + c15;
                #pragma unroll
                for (int r = 0; r < 4; ++r)
                    dst[(size_t)(b * NN + n0 + quad * 4 + r) * 32 + m] = f2bf1(acc[r]);
            } else {
                int c = mt * 16 + c15 - 64;
                int2 pk;
                pk.x = pack2bf(acc[0], acc[1]);
                pk.y = pack2bf(acc[2], acc[3]);
                *(int2*)(vbf + (size_t)b * CC * NN + (size_t)c * NN + n0 + quad * 4) = pk;
            }
        }
    }
}

// ---------------- fused flash attention: block = 256c x 64i x all-j, 8 waves
// wave PV role: mg=w&3 -> c rows [mg*64,+64), nh=w>>2 -> i subcols {nh*32, nh*32+16}
// wave QK role: jsub=w&3, i subcols {nh*32, nh*32+16}
__global__ __launch_bounds__(512, 2) void flash_attn(
        const short* __restrict__ qbf, const short* __restrict__ kbf,
        const short* __restrict__ vbf, const float* __restrict__ x,
        const float* __restrict__ gamma, float* __restrict__ out) {
    __shared__ char lds[75264];  // Vt 2x32KB @0 | Pt 8KB @65536 | lred 1KB @73728

    int bid = blockIdx.x;
    int b = bid & 3, i0 = (bid >> 2) * 64;   // batch -> XCD pair (K/V L2-resident)
    int t = threadIdx.x;
    int w = t >> 6, lane = t & 63, quad = lane >> 4, c15 = lane & 15;
    int mg = w & 3, nh = w >> 2, jsub = w & 3;

    const short* qb = qbf + (size_t)b * NN * 32;
    const short* kb = kbf + (size_t)b * NN * 32;
    const short* vb = vbf + (size_t)b * CC * NN;

    // Q fragments (B-operand), i = i0 + nh*32 (+16) + c15
    bh8 qf0 = *(const bh8*)(qb + (size_t)(i0 + nh * 32 + c15) * 32 + quad * 8);
    bh8 qf1 = *(const bh8*)(qb + (size_t)(i0 + nh * 32 + 16 + c15) * 32 + quad * 8);

    // V staging global address: lane l covers row w*32 + r*8 + (l>>3),
    // logical granule (l&7)^((l>>3)&7) (XOR swizzle). LDS dst is WAVE-UNIFORM
    // (HW places lane l at base + l*16) — per guide m104/m108.
    int vrow = w * 32 + (lane >> 3);
    int glog = (lane & 7) ^ ((lane >> 3) & 7);
    const short* vsg = vb + (size_t)vrow * NN + glog * 8;
    char* vdst = lds + w * 4096;             // uniform per wave

    // K pointer for this wave's j-subtile (A-operand frags straight from global/L2)
    const short* kptr = kb + (size_t)(jsub * 16 + c15) * 32 + quad * 8;

    short* Pt = (short*)(lds + 65536);
    float* lred = (float*)(lds + 73728);

    f32x4 acc[4][2];
    #pragma unroll
    for (int ms = 0; ms < 4; ++ms) {
        acc[ms][0] = (f32x4){0.f, 0.f, 0.f, 0.f};
        acc[ms][1] = (f32x4){0.f, 0.f, 0.f, 0.f};
    }
    float lsum0 = 0.f, lsum1 = 0.f;
    const f32x4 initc = {-12.f, -12.f, -12.f, -12.f};  // softmax shift folded into C

    // prologue: stage V buf0, load K frag for step 0
    #pragma unroll
    for (int r = 0; r < 4; ++r) gld16(vsg + r * 8 * NN, vdst + r * 1024);
    bh8 kf = *(const bh8*)kptr;
    __asm__ volatile("s_waitcnt vmcnt(0)" ::: "memory");
    __syncthreads();   // buf0 staged + visible

    for (int jt = 0; jt < 64; ++jt) {
        int cur = jt & 1;
        // ---- QK: S^T tile (A=K j-rows, B=Q i-cols), exp, pack, P->LDS
        f32x4 sa0 = __builtin_amdgcn_mfma_f32_16x16x32_bf16(kf, qf0, initc, 0, 0, 0);
        f32x4 sa1 = __builtin_amdgcn_mfma_f32_16x16x32_bf16(kf, qf1, initc, 0, 0, 0);
        float p0[4], p1[4];
        #pragma unroll
        for (int r = 0; r < 4; ++r) {
            p0[r] = __expf(sa0[r]); lsum0 += p0[r];
            p1[r] = __expf(sa1[r]); lsum1 += p1[r];
        }
        int g = jsub * 2 + (quad >> 1);
        int pb0 = (nh * 32 + c15) * 128 + ((g ^ (c15 & 7)) * 16) + (quad & 1) * 8;
        *(int2*)((char*)Pt + pb0) = make_int2(pack2bf(p0[0], p0[1]), pack2bf(p0[2], p0[3]));
        *(int2*)((char*)Pt + pb0 + 2048) = make_int2(pack2bf(p1[0], p1[1]), pack2bf(p1[2], p1[3]));
        // K prefetch for next step (wrapped index: no undef at jt=63)
        int jn = (jt + 1) & 63;
        bh8 kfn = *(const bh8*)(kptr + (size_t)jn * 2048);
        __syncthreads();   // P visible to all waves

        // ---- stage next V tile into the other buffer
        if (jt < 63) {
            const short* vs = vsg + (jt + 1) * 64;
            char* vd = vdst + ((cur ^ 1) << 15);   // uniform per wave
            #pragma unroll
            for (int r = 0; r < 4; ++r) gld16(vs + r * 8 * NN, vd + r * 1024);
        }

        // ---- PV: O^T(64c x 32i per wave) += V(A) . P(B)
        const char* Vb = lds + cur * 32768;
        #pragma unroll
        for (int kk = 0; kk < 2; ++kk) {
            int gs = ((kk * 4 + quad) ^ (c15 & 7)) * 16;
            bh8 pfa = *(const bh8*)((char*)Pt + (nh * 32 + c15) * 128 + gs);
            bh8 pfb = *(const bh8*)((char*)Pt + (nh * 32 + 16 + c15) * 128 + gs);
            #pragma unroll
            for (int ms = 0; ms < 4; ++ms) {
                int c = mg * 64 + ms * 16 + c15;
                bh8 vf = *(const bh8*)(Vb + c * 128 + gs);
                acc[ms][0] = __builtin_amdgcn_mfma_f32_16x16x32_bf16(vf, pfa, acc[ms][0], 0, 0, 0);
                acc[ms][1] = __builtin_amdgcn_mfma_f32_16x16x32_bf16(vf, pfb, acc[ms][1], 0, 0, 0);
            }
        }
        kf = kfn;
        __asm__ volatile("s_waitcnt vmcnt(0)" ::: "memory");
        __syncthreads();   // V reads done + next staging drained + visible
    }

    // ---- softmax denominators: quad-reduce, then cross-wave (4 jsubs) via LDS
    lsum0 += __shfl_xor(lsum0, 16); lsum0 += __shfl_xor(lsum0, 32);
    lsum1 += __shfl_xor(lsum1, 16); lsum1 += __shfl_xor(lsum1, 32);
    if (lane < 16) {
        lred[w * 32 + lane] = lsum0;
        lred[w * 32 + 16 + lane] = lsum1;
    }
    __syncthreads();
    float l0 = lred[(nh * 4 + 0) * 32 + c15] + lred[(nh * 4 + 1) * 32 + c15]
             + lred[(nh * 4 + 2) * 32 + c15] + lred[(nh * 4 + 3) * 32 + c15];
    float l1 = lred[(nh * 4 + 0) * 32 + 16 + c15] + lred[(nh * 4 + 1) * 32 + 16 + c15]
             + lred[(nh * 4 + 2) * 32 + 16 + c15] + lred[(nh * 4 + 3) * 32 + 16 + c15];
    float linv0 = 1.0f / l0, linv1 = 1.0f / l1;

    float gm = gamma[0];
    const float* xb2 = x + (size_t)b * CC * NN;
    float* ob = out + (size_t)b * CC * NN;
    int ia = i0 + nh * 32 + c15, ib2 = ia + 16;
    #pragma unroll
    for (int ms = 0; ms < 4; ++ms) {
        #pragma unroll
        for (int r = 0; r < 4; ++r) {
            int c = mg * 64 + ms * 16 + quad * 4 + r;
            ob[(size_t)c * NN + ia]  = gm * acc[ms][0][r] * linv0 + xb2[(size_t)c * NN + ia];
            ob[(size_t)c * NN + ib2] = gm * acc[ms][1][r] * linv1 + xb2[(size_t)c * NN + ib2];
        }
    }
}

extern "C" void kernel_launch(void* const* d_in, const int* in_sizes, int n_in,
                              void* d_out, int out_size, void* d_ws, size_t ws_size,
                              hipStream_t stream) {
    const float* x     = (const float*)d_in[0];
    const float* Wq    = (const float*)d_in[1];
    const float* bq    = (const float*)d_in[2];
    const float* Wk    = (const float*)d_in[3];
    const float* bk    = (const float*)d_in[4];
    const float* Wv    = (const float*)d_in[5];
    const float* bv    = (const float*)d_in[6];
    const float* gamma = (const float*)d_in[7];
    float* out = (float*)d_out;
    char*  ws  = (char*)d_ws;
    short* Wpk  = (short*)(ws + WPK_OFF);
    float* ball = (float*)(ws + BALL_OFF);
    short* qbf  = (short*)(ws + QBF_OFF);
    short* kbf  = (short*)(ws + KBF_OFF);
    short* vbf  = (short*)(ws + VBF_OFF);

    prep_w<<<40, 256, 0, stream>>>(Wq, bq, Wk, bk, Wv, bv, Wpk, ball);
    proj<<<256, 256, 0, stream>>>(x, Wpk, ball, qbf, kbf, vbf);
    flash_attn<<<256, 512, 0, stream>>>(qbf, kbf, vbf, x, gamma, out);
}

// Round 6
// 142.402 us; speedup vs baseline: 4.2158x; 1.1257x over previous
//
#include <hip/hip_runtime.h>

#define BB 4
#define CC 256
#define NN 4096

typedef __attribute__((ext_vector_type(8))) short bh8;
typedef __attribute__((ext_vector_type(4))) float f32x4;

// workspace layout (bytes)
#define WPK_OFF  0                        // 20*8*64*8 bf16 = 163840 (B-frag packed W)
#define BALL_OFF 163840                   // 320 f32
#define QBF_OFF  165888                   // B*N*32 bf16 = 1 MB
#define KBF_OFF  (165888 + 1048576)
#define VBF_OFF  (165888 + 2097152)       // B*C*N bf16 = 8 MB  -> end ~10.4 MB

typedef const __attribute__((address_space(1))) void* gas_t;
typedef __attribute__((address_space(3))) void* las_t;
__device__ inline void gld16(const void* g, void* l) {
    __builtin_amdgcn_global_load_lds((gas_t)g, (las_t)l, 16, 0, 0);
}

__device__ inline int pack2bf(float a, float b) {
    unsigned ua = __builtin_bit_cast(unsigned, a) + 0x8000u;
    unsigned ub = __builtin_bit_cast(unsigned, b) + 0x8000u;
    return (int)__builtin_amdgcn_perm(ub, ua, 0x07060302u);
}
__device__ inline short f2bf1(float a) {
    return (short)((__builtin_bit_cast(unsigned, a) + 0x8000u) >> 16);
}

// ---------------- prep: Wpk B-fragments + ball
__global__ __launch_bounds__(256) void prep_w(const float* __restrict__ Wq,
        const float* __restrict__ bq, const float* __restrict__ Wk,
        const float* __restrict__ bk, const float* __restrict__ Wv,
        const float* __restrict__ bv, short* __restrict__ Wpk,
        float* __restrict__ ball) {
    int tid = blockIdx.x * 256 + threadIdx.x;
    if (tid < 10240) {
        int lane = tid & 63;
        int fc = tid >> 6;                 // mt*8 + ck
        int mt = fc >> 3, ck = fc & 7;
        int m = mt * 16 + (lane & 15);
        int c0 = ck * 32 + (lane >> 4) * 8;
        const float* wrow;
        if (m < 32)      wrow = Wq + m * 256;
        else if (m < 64) wrow = Wk + (m - 32) * 256;
        else             wrow = Wv + (m - 64) * 256;
        int d[4];
        #pragma unroll
        for (int p = 0; p < 4; ++p)
            d[p] = pack2bf(wrow[c0 + 2 * p], wrow[c0 + 2 * p + 1]);
        *(int4*)(Wpk + tid * 8) = make_int4(d[0], d[1], d[2], d[3]);
    }
    if (tid < 320) {
        float b2 = tid < 32 ? bq[tid] : (tid < 64 ? bk[tid - 32] : bv[tid - 64]);
        ball[tid] = b2;
    }
}

// ---------------- projections as MFMA GEMM, m-split x2 for occupancy
// wave = (16-row n-tile, m-half): 2048 waves, 2 blocks/CU.
__global__ __launch_bounds__(256) void proj(const float* __restrict__ x,
        const short* __restrict__ Wpk, const float* __restrict__ ball,
        short* __restrict__ qbf, short* __restrict__ kbf,
        short* __restrict__ vbf) {
    int t = threadIdx.x;
    int w = t >> 6, lane = t & 63, quad = lane >> 4, c15 = lane & 15;
    int gw = blockIdx.x * 4 + w;           // 0..2047
    int tile = gw >> 1, mh = gw & 1;       // waves sharing a tile share the block (L1)
    int b = tile >> 8, n0 = (tile & 255) * 16;
    const float* xb = x + (size_t)b * CC * NN;

    // A-frags: m = c15 (row n0+c15), k = quad*8+e, over 8 k-chunks of 32
    bh8 af[8];
    #pragma unroll
    for (int ck = 0; ck < 8; ++ck) {
        float v[8];
        #pragma unroll
        for (int e = 0; e < 8; ++e)
            v[e] = xb[(size_t)(ck * 32 + quad * 8 + e) * NN + n0 + c15];
        int d[4];
        #pragma unroll
        for (int p = 0; p < 4; ++p) d[p] = pack2bf(v[2 * p], v[2 * p + 1]);
        af[ck] = __builtin_bit_cast(bh8, make_int4(d[0], d[1], d[2], d[3]));
    }

    // this wave's 5 m-pairs (10 of 20 m-tiles)
    #pragma unroll
    for (int mpi = 0; mpi < 5; ++mpi) {
        int mp = mh * 5 + mpi;
        int mtA = mp * 2, mtB = mp * 2 + 1;
        float blA = ball[mtA * 16 + c15], blB = ball[mtB * 16 + c15];
        f32x4 accA = {blA, blA, blA, blA}, accB = {blB, blB, blB, blB};
        #pragma unroll
        for (int ck = 0; ck < 8; ++ck) {
            bh8 wfA = *(const bh8*)(Wpk + ((mtA * 8 + ck) * 64 + lane) * 8);
            bh8 wfB = *(const bh8*)(Wpk + ((mtB * 8 + ck) * 64 + lane) * 8);
            accA = __builtin_amdgcn_mfma_f32_16x16x32_bf16(af[ck], wfA, accA, 0, 0, 0);
            accB = __builtin_amdgcn_mfma_f32_16x16x32_bf16(af[ck], wfB, accB, 0, 0, 0);
        }
        #pragma unroll
        for (int half = 0; half < 2; ++half) {
            int mt = mp * 2 + half;
            f32x4 acc = half ? accB : accA;
            if (mt < 4) {
                short* dst = (mt < 2) ? qbf : kbf;
                int m = (mt & 1) * 16 + c15;
                #pragma unroll
                for (int r = 0; r < 4; ++r)
                    dst[(size_t)(b * NN + n0 + quad * 4 + r) * 32 + m] = f2bf1(acc[r]);
            } else {
                int c = mt * 16 + c15 - 64;
                int2 pk;
                pk.x = pack2bf(acc[0], acc[1]);
                pk.y = pack2bf(acc[2], acc[3]);
                *(int2*)(vbf + (size_t)b * CC * NN + (size_t)c * NN + n0 + quad * 4) = pk;
            }
        }
    }
}

// ---------------- fused flash attention: block = 256c x 64i x all-j, 8 waves
// SINGLE barrier per step: P double-buffered, V double-buffered, V-DMA issued
// AFTER the barrier (so vmcnt(0)@barrier waits the PREVIOUS step's DMA only).
__global__ __launch_bounds__(512, 2) void flash_attn(
        const short* __restrict__ qbf, const short* __restrict__ kbf,
        const short* __restrict__ vbf, const float* __restrict__ x,
        const float* __restrict__ gamma, float* __restrict__ out) {
    __shared__ char lds[82944];  // V 2x32KB @0 | P 2x8KB @65536 | lred 1KB @81920

    int bid = blockIdx.x;
    int b = bid & 3, i0 = (bid >> 2) * 64;   // batch -> XCD pair (K/V L2-resident)
    int t = threadIdx.x;
    int w = t >> 6, lane = t & 63, quad = lane >> 4, c15 = lane & 15;
    int mg = w & 3, nh = w >> 2, jsub = w & 3;

    const short* qb = qbf + (size_t)b * NN * 32;
    const short* kb = kbf + (size_t)b * NN * 32;
    const short* vb = vbf + (size_t)b * CC * NN;

    // Q fragments (B-operand), i = i0 + nh*32 (+16) + c15
    bh8 qf0 = *(const bh8*)(qb + (size_t)(i0 + nh * 32 + c15) * 32 + quad * 8);
    bh8 qf1 = *(const bh8*)(qb + (size_t)(i0 + nh * 32 + 16 + c15) * 32 + quad * 8);

    // V staging: lane l covers row w*32 + r*8 + (l>>3), granule (l&7)^((l>>3)&7)
    // (XOR swizzle); LDS dst is WAVE-UNIFORM (HW: lane l -> base + l*16).
    int vrow = w * 32 + (lane >> 3);
    int glog = (lane & 7) ^ ((lane >> 3) & 7);
    const short* vsg = vb + (size_t)vrow * NN + glog * 8;
    char* vdst = lds + w * 4096;             // uniform per wave

    // K pointer for this wave's j-subtile (A-frags straight from global/L2)
    const short* kptr = kb + (size_t)(jsub * 16 + c15) * 32 + quad * 8;

    char* Pt = lds + 65536;
    float* lred = (float*)(lds + 81920);

    f32x4 acc[4][2];
    #pragma unroll
    for (int ms = 0; ms < 4; ++ms) {
        acc[ms][0] = (f32x4){0.f, 0.f, 0.f, 0.f};
        acc[ms][1] = (f32x4){0.f, 0.f, 0.f, 0.f};
    }
    float lsum0 = 0.f, lsum1 = 0.f;
    const f32x4 initc = {-12.f, -12.f, -12.f, -12.f};  // softmax shift folded into C

    // prologue: stage V buf0, load K frag for step 0
    #pragma unroll
    for (int r = 0; r < 4; ++r) gld16(vsg + r * 8 * NN, vdst + r * 1024);
    bh8 kf = *(const bh8*)kptr;
    __syncthreads();   // drains vmcnt -> buf0 staged

    for (int jt = 0; jt < 64; ++jt) {
        int cur = jt & 1;
        // ---- QK: S^T tile (A=K j-rows, B=Q i-cols), exp, pack, P->LDS[cur]
        f32x4 sa0 = __builtin_amdgcn_mfma_f32_16x16x32_bf16(kf, qf0, initc, 0, 0, 0);
        f32x4 sa1 = __builtin_amdgcn_mfma_f32_16x16x32_bf16(kf, qf1, initc, 0, 0, 0);
        // K prefetch for next step (independent; issued early to hide L2 latency)
        bh8 kfn = *(const bh8*)(kptr + (size_t)((jt + 1) & 63) * 2048);
        float p0[4], p1[4];
        #pragma unroll
        for (int r = 0; r < 4; ++r) {
            p0[r] = __expf(sa0[r]); lsum0 += p0[r];
            p1[r] = __expf(sa1[r]); lsum1 += p1[r];
        }
        char* Ptc = Pt + cur * 8192;
        int g = jsub * 2 + (quad >> 1);
        int pb0 = (nh * 32 + c15) * 128 + ((g ^ (c15 & 7)) * 16) + (quad & 1) * 8;
        *(int2*)(Ptc + pb0) = make_int2(pack2bf(p0[0], p0[1]), pack2bf(p0[2], p0[3]));
        *(int2*)(Ptc + pb0 + 2048) = make_int2(pack2bf(p1[0], p1[1]), pack2bf(p1[2], p1[3]));

        // single barrier: publishes P[cur]; vmcnt(0) drain covers the V-DMA
        // issued after the PREVIOUS barrier (full step of slack)
        __syncthreads();

        // ---- issue next V staging AFTER the barrier (read-safety by barrier order)
        if (jt < 63) {
            const short* vs = vsg + (jt + 1) * 64;
            char* vd = vdst + ((cur ^ 1) << 15);   // uniform per wave
            #pragma unroll
            for (int r = 0; r < 4; ++r) gld16(vs + r * 8 * NN, vd + r * 1024);
        }

        // ---- PV: O^T(64c x 32i per wave) += V(A) . P(B) from V[cur], P[cur]
        const char* Vb = lds + cur * 32768;
        #pragma unroll
        for (int kk = 0; kk < 2; ++kk) {
            int gs = ((kk * 4 + quad) ^ (c15 & 7)) * 16;
            bh8 pfa = *(const bh8*)(Ptc + (nh * 32 + c15) * 128 + gs);
            bh8 pfb = *(const bh8*)(Ptc + (nh * 32 + 16 + c15) * 128 + gs);
            #pragma unroll
            for (int ms = 0; ms < 4; ++ms) {
                int c = mg * 64 + ms * 16 + c15;
                bh8 vf = *(const bh8*)(Vb + c * 128 + gs);
                acc[ms][0] = __builtin_amdgcn_mfma_f32_16x16x32_bf16(vf, pfa, acc[ms][0], 0, 0, 0);
                acc[ms][1] = __builtin_amdgcn_mfma_f32_16x16x32_bf16(vf, pfb, acc[ms][1], 0, 0, 0);
            }
        }
        kf = kfn;
    }

    // ---- softmax denominators: quad-reduce, then cross-wave (4 jsubs) via LDS
    lsum0 += __shfl_xor(lsum0, 16); lsum0 += __shfl_xor(lsum0, 32);
    lsum1 += __shfl_xor(lsum1, 16); lsum1 += __shfl_xor(lsum1, 32);
    __syncthreads();   // all PV reads of last step done before lred reuse region
    if (lane < 16) {
        lred[w * 32 + lane] = lsum0;
        lred[w * 32 + 16 + lane] = lsum1;
    }
    __syncthreads();
    float l0 = lred[(nh * 4 + 0) * 32 + c15] + lred[(nh * 4 + 1) * 32 + c15]
             + lred[(nh * 4 + 2) * 32 + c15] + lred[(nh * 4 + 3) * 32 + c15];
    float l1 = lred[(nh * 4 + 0) * 32 + 16 + c15] + lred[(nh * 4 + 1) * 32 + 16 + c15]
             + lred[(nh * 4 + 2) * 32 + 16 + c15] + lred[(nh * 4 + 3) * 32 + 16 + c15];
    float linv0 = 1.0f / l0, linv1 = 1.0f / l1;

    float gm = gamma[0];
    const float* xb2 = x + (size_t)b * CC * NN;
    float* ob = out + (size_t)b * CC * NN;
    int ia = i0 + nh * 32 + c15, ib2 = ia + 16;
    #pragma unroll
    for (int ms = 0; ms < 4; ++ms) {
        #pragma unroll
        for (int r = 0; r < 4; ++r) {
            int c = mg * 64 + ms * 16 + quad * 4 + r;
            ob[(size_t)c * NN + ia]  = gm * acc[ms][0][r] * linv0 + xb2[(size_t)c * NN + ia];
            ob[(size_t)c * NN + ib2] = gm * acc[ms][1][r] * linv1 + xb2[(size_t)c * NN + ib2];
        }
    }
}

extern "C" void kernel_launch(void* const* d_in, const int* in_sizes, int n_in,
                              void* d_out, int out_size, void* d_ws, size_t ws_size,
                              hipStream_t stream) {
    const float* x     = (const float*)d_in[0];
    const float* Wq    = (const float*)d_in[1];
    const float* bq    = (const float*)d_in[2];
    const float* Wk    = (const float*)d_in[3];
    const float* bk    = (const float*)d_in[4];
    const float* Wv    = (const float*)d_in[5];
    const float* bv    = (const float*)d_in[6];
    const float* gamma = (const float*)d_in[7];
    float* out = (float*)d_out;
    char*  ws  = (char*)d_ws;
    short* Wpk  = (short*)(ws + WPK_OFF);
    float* ball = (float*)(ws + BALL_OFF);
    short* qbf  = (short*)(ws + QBF_OFF);
    short* kbf  = (short*)(ws + KBF_OFF);
    short* vbf  = (short*)(ws + VBF_OFF);

    prep_w<<<40, 256, 0, stream>>>(Wq, bq, Wk, bk, Wv, bv, Wpk, ball);
    proj<<<512, 256, 0, stream>>>(x, Wpk, ball, qbf, kbf, vbf);
    flash_attn<<<256, 512, 0, stream>>>(qbf, kbf, vbf, x, gamma, out);
}